// Round 7
// baseline (110.655 us; speedup 1.0000x reference)
//
#include <hip/hip_runtime.h>
#include <hip/hip_fp16.h>

constexpr int kNodes = 50000;
constexpr int kEdges = 500000;
constexpr int kInF   = 128;
constexpr int kOutF  = 16;

typedef float    f32x4 __attribute__((ext_vector_type(4)));
typedef __fp16   h16x2 __attribute__((ext_vector_type(2)));
typedef _Float16 f16x4 __attribute__((ext_vector_type(4)));

static __device__ inline unsigned int pack_f16(float a, float b) {
  const h16x2 h = __builtin_amdgcn_cvt_pkrtz(a, b);
  return __builtin_bit_cast(unsigned int, h);
}

// ---------------------------------------------------------------------------
// Kernel 1: support[n][f] = sum_k x[n][k]*W[k][f] (f32)  AND  out_h[n][f] = 0.
// 4 threads per node; thread owns one float4 of the 16 outputs.
// ---------------------------------------------------------------------------
__global__ __launch_bounds__(256) void support_init_kernel(
    const float* __restrict__ x, const float* __restrict__ weight,
    float* __restrict__ support, _Float16* __restrict__ out_h) {
  __shared__ f32x4 w4[kInF][kOutF / 4];  // w4[k][f4]
  for (int i = threadIdx.x; i < kInF * (kOutF / 4); i += 256) {
    w4[i / (kOutF / 4)][i % (kOutF / 4)] =
        reinterpret_cast<const f32x4*>(weight)[i];
  }
  __syncthreads();

  const int gid  = blockIdx.x * 256 + threadIdx.x;
  const int node = gid >> 2;
  const int f4   = gid & 3;
  if (node >= kNodes) return;

  f32x4 acc = {0.f, 0.f, 0.f, 0.f};
  const f32x4* xr = reinterpret_cast<const f32x4*>(x + (size_t)node * kInF);
#pragma unroll
  for (int k4 = 0; k4 < kInF / 4; ++k4) {
    const f32x4 v = xr[k4];
#pragma unroll
    for (int kk = 0; kk < 4; ++kk) {
      acc += v[kk] * w4[k4 * 4 + kk][f4];
    }
  }

  reinterpret_cast<f32x4*>(support + (size_t)node * kOutF)[f4] = acc;
  const uint2 z = {0u, 0u};
  reinterpret_cast<uint2*>(out_h + (size_t)node * kOutF)[f4] = z;
}

// ---------------------------------------------------------------------------
// Kernel 2: whole-wave-per-edge (round-6 geometry, unchanged):
//   stream load : 1 dwordx4/lane, the edge's 1 KB contiguous per wave
//   gather      : 4 distinct 16 B addrs/edge (broadcast within 16-lane groups)
//   dot finish  : shfl_xor 16 + 32
// NEW accumulation path: shfl_xor(1) pairs even/odd rows, cvt_pkrtz packs,
// 8 lanes/edge issue global_atomic_pk_add_f16 -> 4M packed atomics (was 8M
// dword atomics), 32 B payload per edge.
// ---------------------------------------------------------------------------
constexpr int kEPW = 8;  // edges per wave; kEdges % (4 waves * kEPW) == 0

__global__ __launch_bounds__(256) void edge_kernel(
    const float* __restrict__ edge_data, const float* __restrict__ support,
    const int* __restrict__ esrc, const int* __restrict__ etgt,
    _Float16* __restrict__ out_h) {
  const int wave = (blockIdx.x * 256 + threadIdx.x) >> 6;
  const int l    = threadIdx.x & 63;
  const int r    = l & 15;   // output row this lane reduces
  const int q    = l >> 4;   // which 4-column quarter this lane loads
  const int e0   = wave * kEPW;

  const f32x4* ed4 = reinterpret_cast<const f32x4*>(edge_data);
  const f32x4* sp4 = reinterpret_cast<const f32x4*>(support);

  f32x4 row[kEPW];
  f32x4 sv[kEPW];
  int   tgt[kEPW];

#pragma unroll
  for (int k = 0; k < kEPW; ++k) {
    const int e = e0 + k;
    const int s = esrc[e];
    tgt[k]      = etgt[e];
    sv[k]       = sp4[(size_t)s * 4 + q];
    row[k]      = ed4[(size_t)e * 64 + (r * 4 + q)];
  }

#pragma unroll
  for (int k = 0; k < kEPW; ++k) {
    float dot = row[k].x * sv[k].x + row[k].y * sv[k].y + row[k].z * sv[k].z +
                row[k].w * sv[k].w;
    dot += __shfl_xor(dot, 16);   // fold quarters: q pairs
    dot += __shfl_xor(dot, 32);   // all lanes now hold full dot of row r
    const float dot_odd = __shfl_xor(dot, 1);  // even r: dot of row r+1
    if (q == 0 && (r & 1) == 0) {
      const unsigned int bits = pack_f16(dot, dot_odd);
      _Float16* dst = out_h + (size_t)tgt[k] * kOutF + r;
      asm volatile("global_atomic_pk_add_f16 %0, %1, off" ::"v"(dst),
                   "v"(bits)
                   : "memory");
    }
  }
}

// ---------------------------------------------------------------------------
// Kernel 3: out[n][f] = (float)out_h[n][f] + bias[f]
// ---------------------------------------------------------------------------
__global__ __launch_bounds__(256) void finalize_kernel(
    const _Float16* __restrict__ out_h, const float* __restrict__ bias,
    float* __restrict__ out) {
  const int tid = blockIdx.x * 256 + threadIdx.x;
  if (tid >= kNodes * 4) return;
  const int node = tid >> 2;
  const int q    = tid & 3;

  const f16x4 h =
      reinterpret_cast<const f16x4*>(out_h + (size_t)node * kOutF)[q];
  const f32x4 b = reinterpret_cast<const f32x4*>(bias)[q];
  f32x4 o;
  o.x = (float)h[0] + b.x;
  o.y = (float)h[1] + b.y;
  o.z = (float)h[2] + b.z;
  o.w = (float)h[3] + b.w;
  reinterpret_cast<f32x4*>(out + (size_t)node * kOutF)[q] = o;
}

// ---------------------------------------------------------------------------
extern "C" void kernel_launch(void* const* d_in, const int* in_sizes, int n_in,
                              void* d_out, int out_size, void* d_ws,
                              size_t ws_size, hipStream_t stream) {
  const float* x         = (const float*)d_in[0];
  const float* weight    = (const float*)d_in[1];
  const float* bias      = (const float*)d_in[2];
  const float* edge_data = (const float*)d_in[3];
  const int*   esrc      = (const int*)d_in[4];
  const int*   etgt      = (const int*)d_in[5];
  float* out = (float*)d_out;

  float*    support = (float*)d_ws;  // 3.2 MB
  _Float16* out_h =
      (_Float16*)((char*)d_ws + (size_t)kNodes * kOutF * sizeof(float));

  support_init_kernel<<<(kNodes * 4 + 255) / 256, 256, 0, stream>>>(
      x, weight, support, out_h);

  // 4 waves/block * kEPW edges/wave = 32 edges per block
  edge_kernel<<<kEdges / (4 * kEPW), 256, 0, stream>>>(edge_data, support,
                                                       esrc, etgt, out_h);

  finalize_kernel<<<(kNodes * 4 + 255) / 256, 256, 0, stream>>>(out_h, bias,
                                                                out);
}

// Round 8
// 108.712 us; speedup vs baseline: 1.0179x; 1.0179x over previous
//
#include <hip/hip_runtime.h>

constexpr int kNodes = 50000;
constexpr int kEdges = 500000;
constexpr int kInF   = 128;
constexpr int kOutF  = 16;

typedef float f32x4 __attribute__((ext_vector_type(4)));

// ---------------------------------------------------------------------------
// Kernel 1 (fused): support[n][f] = sum_k x[n][k]*W[k][f]  AND  out[n][f]=bias[f]
// 4 threads per node; thread owns one float4 (f4) of the 16 outputs.
// ---------------------------------------------------------------------------
__global__ __launch_bounds__(256) void support_init_kernel(
    const float* __restrict__ x, const float* __restrict__ weight,
    const float* __restrict__ bias, float* __restrict__ support,
    float* __restrict__ out) {
  __shared__ f32x4 w4[kInF][kOutF / 4];  // w4[k][f4]
  for (int i = threadIdx.x; i < kInF * (kOutF / 4); i += 256) {
    w4[i / (kOutF / 4)][i % (kOutF / 4)] =
        reinterpret_cast<const f32x4*>(weight)[i];
  }
  __shared__ f32x4 b4[kOutF / 4];
  if (threadIdx.x < kOutF / 4)
    b4[threadIdx.x] = reinterpret_cast<const f32x4*>(bias)[threadIdx.x];
  __syncthreads();

  const int gid  = blockIdx.x * 256 + threadIdx.x;
  const int node = gid >> 2;
  const int f4   = gid & 3;
  if (node >= kNodes) return;

  f32x4 acc = {0.f, 0.f, 0.f, 0.f};
  const f32x4* xr = reinterpret_cast<const f32x4*>(x + (size_t)node * kInF);
#pragma unroll
  for (int k4 = 0; k4 < kInF / 4; ++k4) {
    const f32x4 v = xr[k4];
#pragma unroll
    for (int kk = 0; kk < 4; ++kk) {
      acc += v[kk] * w4[k4 * 4 + kk][f4];
    }
  }

  reinterpret_cast<f32x4*>(support + (size_t)node * kOutF)[f4] = acc;
  reinterpret_cast<f32x4*>(out + (size_t)node * kOutF)[f4] = b4[f4];
}

// ---------------------------------------------------------------------------
// Kernel 2: whole-wave-per-edge (round-6 geometry):
//   stream load : 1 dwordx4/lane, the edge's 1 KB contiguous per wave
//   gather      : 4 distinct 16 B addrs/edge (broadcast within 16-lane groups)
//   dot finish  : shfl_xor 16 + 32; lanes with q==0 do the fp32 atomic
//   (16 consecutive dwords -> single-line coalesced atomic)
// Changes vs round 6: wave id scalarized via readfirstlane so esrc/etgt
// loads become s_load on the scalar cache; kEPW 8 -> 10.
// ---------------------------------------------------------------------------
constexpr int kEPW = 10;  // edges per wave; 500000 = 12500 blocks * 4 * 10

__global__ __launch_bounds__(256) void edge_kernel(
    const float* __restrict__ edge_data, const float* __restrict__ support,
    const int* __restrict__ esrc, const int* __restrict__ etgt,
    float* __restrict__ out) {
  // Force wave-uniformity so index loads scalarize.
  const int wib  = __builtin_amdgcn_readfirstlane(threadIdx.x >> 6);
  const int wave = blockIdx.x * 4 + wib;
  const int l    = threadIdx.x & 63;
  const int r    = l & 15;   // output row this lane reduces
  const int q    = l >> 4;   // which 4-column quarter this lane loads
  const int e0   = wave * kEPW;

  const f32x4* ed4 = reinterpret_cast<const f32x4*>(edge_data);
  const f32x4* sp4 = reinterpret_cast<const f32x4*>(support);

  f32x4 row[kEPW];
  f32x4 sv[kEPW];
  int   tgt[kEPW];

#pragma unroll
  for (int k = 0; k < kEPW; ++k) {
    const int e = e0 + k;
    const int s = esrc[e];
    tgt[k]      = etgt[e];
    sv[k]       = sp4[(size_t)s * 4 + q];
    row[k]      = ed4[(size_t)e * 64 + (r * 4 + q)];
  }

#pragma unroll
  for (int k = 0; k < kEPW; ++k) {
    float dot = row[k].x * sv[k].x + row[k].y * sv[k].y + row[k].z * sv[k].z +
                row[k].w * sv[k].w;
    dot += __shfl_xor(dot, 16);  // fold quarter pairs
    dot += __shfl_xor(dot, 32);  // all lanes hold full dot of row r
    if (q == 0) atomicAdd(&out[(size_t)tgt[k] * kOutF + r], dot);
  }
}

// ---------------------------------------------------------------------------
extern "C" void kernel_launch(void* const* d_in, const int* in_sizes, int n_in,
                              void* d_out, int out_size, void* d_ws,
                              size_t ws_size, hipStream_t stream) {
  const float* x         = (const float*)d_in[0];
  const float* weight    = (const float*)d_in[1];
  const float* bias      = (const float*)d_in[2];
  const float* edge_data = (const float*)d_in[3];
  const int*   esrc      = (const int*)d_in[4];
  const int*   etgt      = (const int*)d_in[5];
  float* out = (float*)d_out;

  float* support = (float*)d_ws;  // kNodes * kOutF * 4 B = 3.2 MB

  support_init_kernel<<<(kNodes * 4 + 255) / 256, 256, 0, stream>>>(
      x, weight, bias, support, out);

  // 4 waves/block * kEPW edges/wave = 40 edges per block
  edge_kernel<<<kEdges / (4 * kEPW), 256, 0, stream>>>(edge_data, support,
                                                       esrc, etgt, out);
}